// Round 1
// 292.416 us; speedup vs baseline: 1.0750x; 1.0750x over previous
//
#include <hip/hip_runtime.h>
#include <hip/hip_bf16.h>

// ============================================================================
// GAT 2-layer forward, round 15.
// r14 post-mortem: k_seg2 at 1.57TB/s L2-miss traffic vs ~2.4TB/s random-fill
// ceiling, MfmaUtil 0 — segs are latency/structure-bound, not fill-bound.
// Changes: (1) seg blocks widened 4->16 nodes, single-pass staging (CHE=512),
// 4 nodes per wave -> 4x longer gather loops, 6250 blocks; (2) gemm2 fused
// into seg1 as a per-block MFMA epilogue on LDS z (W2ext pretransposed bf16 in
// k_init, rows padded to 72 shorts vs 128B-stride bank conflict) — kills the
// 51.2MB bufO round trip and one dispatch. Numeric rounding points unchanged.
// Facts: fp32 in/out, int32 edge_index, N=100000 E=1600000, bf16 h.
// ============================================================================

typedef __hip_bfloat16 bf16;
typedef unsigned short ushort;
typedef unsigned char uchar;
typedef __attribute__((ext_vector_type(8))) short short8;
typedef __attribute__((ext_vector_type(4))) float f32x4;

#define NN 100000
#define EE 1600000
#define BKB 9
#define BKN (1 << BKB)
#define NBK ((NN + BKN - 1) >> BKB)   // 196
#define CAP 10240                     // arena slots per bucket (max ~8.5K)
#define TILE 4096
#define EPT 16
#define NT ((EE + TILE - 1) / TILE)
#define BN 16                         // nodes per seg block (16 | 512 bucket)
#define CHE 512                       // max edges/block: mean 256, +16 sigma

__device__ __forceinline__ float relu_np(float v) { return (v < 0.f) ? 0.f : v; }
__device__ __forceinline__ float lrelu(float v) { return v > 0.f ? v : 0.2f * v; }
__device__ __forceinline__ ushort f2bf(float f) {
    __hip_bfloat16 h = __float2bfloat16(f);
    return *reinterpret_cast<ushort*>(&h);
}
__device__ __forceinline__ float bf2f(ushort u) {
    unsigned int x = ((unsigned int)u) << 16;
    return __uint_as_float(x);
}

// ---- init arena cursors + build W2ext^T bf16 [80][64] ----------------------
// n<64: W2 col n; n==64: W2 @ aS2; n==65: W2 @ aD2; n>=66: zero pad.
__global__ __launch_bounds__(256) void k_init(
    int* __restrict__ gcur, const float* __restrict__ W2,
    const float* __restrict__ aS2, const float* __restrict__ aD2,
    ushort* __restrict__ wExt)
{
    const int tid = threadIdx.x;
    if (tid < NBK) gcur[tid] = tid * CAP;
    for (int i = tid; i < 80 * 64; i += 256) {
        int n = i >> 6, k = i & 63;
        float v = 0.f;
        if (n < 64) {
            v = W2[k * 64 + n];
        } else if (n == 64) {
            for (int c = 0; c < 64; ++c) v = fmaf(W2[k * 64 + c], aS2[c], v);
        } else if (n == 65) {
            for (int c = 0; c < 64; ++c) v = fmaf(W2[k * 64 + c], aD2[c], v);
        }
        wExt[i] = f2bf(v);
    }
}

// ---- partition into per-bucket arenas (block-aggregated writes) ------------
__global__ __launch_bounds__(256) void k_part(
    const int* __restrict__ src, const int* __restrict__ dst,
    int* __restrict__ gcur, int* __restrict__ pairs, int E)
{
    __shared__ int lh[NBK];
    __shared__ int lbase[NBK];
    const int tid = threadIdx.x;
    for (int i = tid; i < NBK; i += 256) lh[i] = 0;
    __syncthreads();
    const int e0 = blockIdx.x * TILE;
    int pk[EPT], bk[EPT], rv[EPT];
    #pragma unroll
    for (int j = 0; j < EPT; ++j) {
        int e = e0 + j * 256 + tid;
        if (e < E) {
            int d = dst[e];
            bk[j] = d >> BKB;
            pk[j] = src[e] | ((d & (BKN - 1)) << 17);
            rv[j] = atomicAdd(&lh[bk[j]], 1);
        }
    }
    __syncthreads();
    for (int i = tid; i < NBK; i += 256)
        lbase[i] = lh[i] ? atomicAdd(&gcur[i], lh[i]) : 0;
    __syncthreads();
    #pragma unroll
    for (int j = 0; j < EPT; ++j) {
        int e = e0 + j * 256 + tid;
        if (e < E) pairs[lbase[bk[j]] + rv[j]] = pk[j];
    }
}

// ---- per-bucket: node hist + scan -> row_ptr + rcnt; scatter col -----------
__global__ __launch_bounds__(256) void k_bucket(
    const int* __restrict__ gcur, const int* __restrict__ pairs,
    int* __restrict__ row_ptr, uchar* __restrict__ rcnt,
    int* __restrict__ col, int N)
{
    __shared__ int hist[BKN];
    __shared__ int sP[256];
    const int b = blockIdx.x;
    const int n0 = b << BKB;
    const int tid = threadIdx.x;
    const int base = b * CAP, endE = gcur[b];
    for (int i = tid; i < BKN; i += 256) hist[i] = 0;
    __syncthreads();
    for (int i = base + tid; i < endE; i += 256)
        atomicAdd(&hist[pairs[i] >> 17], 1);
    __syncthreads();
    int a0 = hist[2 * tid], a1 = hist[2 * tid + 1];
    int tot = a0 + a1;
    sP[tid] = tot;
    __syncthreads();
    for (int off = 1; off < 256; off <<= 1) {
        int t = (tid >= off) ? sP[tid - off] : 0;
        __syncthreads();
        sP[tid] += t;
        __syncthreads();
    }
    const int excl = sP[tid] - tot;
    const int c0 = base + excl;
    hist[2 * tid] = c0;
    hist[2 * tid + 1] = c0 + a0;
    if (n0 + 2 * tid < N) {
        row_ptr[n0 + 2 * tid] = c0;
        rcnt[n0 + 2 * tid] = (uchar)a0;
    }
    if (n0 + 2 * tid + 1 < N) {
        row_ptr[n0 + 2 * tid + 1] = c0 + a0;
        rcnt[n0 + 2 * tid + 1] = (uchar)a1;
    }
    __syncthreads();
    for (int i = base + tid; i < endE; i += 256) {
        int pr = pairs[i];
        int p = atomicAdd(&hist[pr >> 17], 1);
        col[p] = pr & 0x1FFFF;
    }
}

// ---------------- GEMM1 (MFMA) with alpha as extra B columns -----------------
__global__ __launch_bounds__(256) void k_gemm1(
    const float* __restrict__ x, const float* __restrict__ W1,
    const float* __restrict__ aS, const float* __restrict__ aD,
    ushort* __restrict__ h1, float* __restrict__ as1, float* __restrict__ ad1,
    int N)
{
    __shared__ ushort wB[64 * 128];
    __shared__ ushort wE[16 * 128];
    const int tid = threadIdx.x;
    for (int i = tid; i < 128 * 64; i += 256) {
        int k = i >> 6, n = i & 63;
        wB[n * 128 + k] = f2bf(W1[i]);
    }
    for (int i = tid; i < 128 * 16; i += 256) {
        int k = i >> 4, j = i & 15;
        float v = 0.f;
        if (j < 8) {
            int h = j & 3;
            const float* av = (j < 4) ? aS : aD;
            for (int c = 0; c < 16; ++c)
                v = fmaf(W1[k * 64 + h * 16 + c], av[h * 16 + c], v);
        }
        wE[j * 128 + k] = f2bf(v);
    }
    __syncthreads();
    const int w = tid >> 6, lane = tid & 63;
    const int m = lane & 15, quad = lane >> 4;
    const int ntiles = N >> 4;
    for (int tile = blockIdx.x * 4 + w; tile < ntiles; tile += gridDim.x * 4) {
        const int row0 = tile << 4;
        f32x4 acc[4] = {f32x4{0,0,0,0}, f32x4{0,0,0,0},
                        f32x4{0,0,0,0}, f32x4{0,0,0,0}};
        f32x4 acc5 = {0, 0, 0, 0};
        const float* xp = x + (size_t)(row0 + m) * 128 + quad * 8;
        #pragma unroll
        for (int ks = 0; ks < 128; ks += 32) {
            f32x4 x0 = *(const f32x4*)(xp + ks);
            f32x4 x1 = *(const f32x4*)(xp + ks + 4);
            short8 a;
            #pragma unroll
            for (int j = 0; j < 4; ++j) a[j] = (short)f2bf(x0[j]);
            #pragma unroll
            for (int j = 0; j < 4; ++j) a[4 + j] = (short)f2bf(x1[j]);
            #pragma unroll
            for (int t = 0; t < 4; ++t) {
                short8 b = *(const short8*)&wB[(t * 16 + m) * 128 + ks + quad * 8];
                acc[t] = __builtin_amdgcn_mfma_f32_16x16x32_bf16(a, b, acc[t], 0, 0, 0);
            }
            short8 b5 = *(const short8*)&wE[m * 128 + ks + quad * 8];
            acc5 = __builtin_amdgcn_mfma_f32_16x16x32_bf16(a, b5, acc5, 0, 0, 0);
        }
        #pragma unroll
        for (int t = 0; t < 4; ++t)
            #pragma unroll
            for (int r = 0; r < 4; ++r)
                h1[(size_t)(row0 + quad * 4 + r) * 64 + t * 16 + m] = f2bf(acc[t][r]);
        #pragma unroll
        for (int r = 0; r < 4; ++r) {
            int row = row0 + quad * 4 + r;
            if (m < 4) as1[row * 4 + m] = acc5[r];
            else if (m < 8) ad1[row * 4 + (m - 4)] = acc5[r];
        }
    }
}

// ---------------- layer-1 seg aggregation + fused layer-2 GEMM ---------------
// 16 nodes/block, single staging pass. Per wave: 4 sequential nodes.
// Epilogue: z=relu(acc/den+b1) -> LDS bf16 [16][72-pad]; 10 MFMAs compute
// h2 = z @ W2ext (16x64x80), ext cols 64/65 -> as2/ad2.
__global__ __launch_bounds__(256) void k_seg1f(
    const int* __restrict__ rp, const uchar* __restrict__ rcnt,
    const int* __restrict__ col,
    const float* __restrict__ as1, const float* __restrict__ ad1,
    const ushort* __restrict__ h1, const float* __restrict__ b1,
    const ushort* __restrict__ wExt,
    ushort* __restrict__ h2, float* __restrict__ as2, float* __restrict__ ad2,
    int N)
{
    __shared__ __align__(16) ushort wS[80 * 72];   // W2ext^T, rows padded 64->72
    __shared__ __align__(16) ushort zS[BN * 72];   // z bf16, rows padded
    __shared__ float pS[CHE * 4];
    __shared__ int colS[CHE];
    __shared__ uchar ndS[CHE];
    __shared__ int sRp[BN + 1];
    __shared__ float bS[64];
    __shared__ float adS[BN * 4];

    const int tid = threadIdx.x;
    const int n0 = blockIdx.x * BN;

    for (int i8 = tid; i8 < 640; i8 += 256) {      // stage W2ext (10KB, L2-hot)
        short8 v = *(const short8*)&wExt[i8 * 8];
        *(short8*)&wS[(i8 >> 3) * 72 + (i8 & 7) * 8] = v;
    }
    if (tid < 64) bS[tid] = b1[tid];
    if (tid < BN * 4) adS[tid] = ad1[(size_t)n0 * 4 + tid];
    if (tid < BN) sRp[tid] = rp[n0 + tid];
    if (tid == BN) sRp[BN] = rp[n0 + BN - 1] + (int)rcnt[n0 + BN - 1];
    __syncthreads();

    const int eb0 = sRp[0];
    const int cnt = min(sRp[BN] - eb0, CHE);       // mean 256, never near 512

    for (int t = tid; t < cnt; t += 256) {
        int ge = eb0 + t;
        colS[t] = col[ge];
        int nd = 0;
        #pragma unroll
        for (int k = 1; k < BN; ++k) nd += (ge >= sRp[k]);
        ndS[t] = (uchar)nd;
    }
    __syncthreads();
    for (int t = tid; t < cnt * 4; t += 256) {
        int e = t >> 2, hh = t & 3;
        float v = as1[(size_t)colS[e] * 4 + hh] + adS[ndS[e] * 4 + hh];
        pS[t] = __expf(lrelu(v));
    }
    __syncthreads();

    const int w = tid >> 6, lane = tid & 63;
    const int slot = lane >> 4, c4 = lane & 15, head = c4 >> 2;
    const int uid = slot * 4 + (c4 & 3);

    for (int nl = 0; nl < 4; ++nl) {
        const int nb = w * 4 + nl;
        const int s_n = sRp[nb] - eb0, e_n = sRp[nb + 1] - eb0;
        float den = 0.f;
        f32x4 accA = {0,0,0,0}, accB = {0,0,0,0};
        for (int i = s_n + uid; i < e_n; i += 16) den += pS[i * 4 + head];
        int i = s_n;
        for (; i + 7 < e_n; i += 8) {
            int lA = i + slot, lB = lA + 4;
            float pA = pS[lA * 4 + head], pB = pS[lB * 4 + head];
            ushort4 hA = *(const ushort4*)&h1[(size_t)colS[lA] * 64 + c4 * 4];
            ushort4 hB = *(const ushort4*)&h1[(size_t)colS[lB] * 64 + c4 * 4];
            accA[0] = fmaf(pA, bf2f(hA.x), accA[0]);
            accA[1] = fmaf(pA, bf2f(hA.y), accA[1]);
            accA[2] = fmaf(pA, bf2f(hA.z), accA[2]);
            accA[3] = fmaf(pA, bf2f(hA.w), accA[3]);
            accB[0] = fmaf(pB, bf2f(hB.x), accB[0]);
            accB[1] = fmaf(pB, bf2f(hB.y), accB[1]);
            accB[2] = fmaf(pB, bf2f(hB.z), accB[2]);
            accB[3] = fmaf(pB, bf2f(hB.w), accB[3]);
        }
        for (; i < e_n; i += 4) {
            int ii = i + slot;
            if (ii < e_n) {
                float p = pS[ii * 4 + head];
                ushort4 hv = *(const ushort4*)&h1[(size_t)colS[ii] * 64 + c4 * 4];
                accA[0] = fmaf(p, bf2f(hv.x), accA[0]);
                accA[1] = fmaf(p, bf2f(hv.y), accA[1]);
                accA[2] = fmaf(p, bf2f(hv.z), accA[2]);
                accA[3] = fmaf(p, bf2f(hv.w), accA[3]);
            }
        }
        den += __shfl_xor(den, 1);
        den += __shfl_xor(den, 2);
        den += __shfl_xor(den, 16);
        den += __shfl_xor(den, 32);
        #pragma unroll
        for (int j = 0; j < 4; ++j) {
            accA[j] += accB[j];
            accA[j] += __shfl_xor(accA[j], 16);
            accA[j] += __shfl_xor(accA[j], 32);
        }
        if (slot == 0) {
            float inv = 1.f / (den + 1e-16f);
            ushort4 zv;
            zv.x = f2bf(relu_np(accA[0] * inv + bS[c4 * 4 + 0]));
            zv.y = f2bf(relu_np(accA[1] * inv + bS[c4 * 4 + 1]));
            zv.z = f2bf(relu_np(accA[2] * inv + bS[c4 * 4 + 2]));
            zv.w = f2bf(relu_np(accA[3] * inv + bS[c4 * 4 + 3]));
            *(ushort4*)&zS[nb * 72 + c4 * 4] = zv;
        }
    }
    __syncthreads();

    // ---- fused gemm2 epilogue: 5 n-tiles over 4 waves (wave0 takes ext) ----
    const int m = c4, quad = slot;
    for (int t = w; t < 5; t += 4) {
        f32x4 acc = {0, 0, 0, 0};
        #pragma unroll
        for (int ks = 0; ks < 64; ks += 32) {
            short8 a = *(const short8*)&zS[m * 72 + ks + quad * 8];
            short8 b = *(const short8*)&wS[(t * 16 + m) * 72 + ks + quad * 8];
            acc = __builtin_amdgcn_mfma_f32_16x16x32_bf16(a, b, acc, 0, 0, 0);
        }
        if (t < 4) {
            #pragma unroll
            for (int r = 0; r < 4; ++r)
                h2[(size_t)(n0 + quad * 4 + r) * 64 + t * 16 + m] = f2bf(acc[r]);
        } else {
            #pragma unroll
            for (int r = 0; r < 4; ++r) {
                int row = n0 + quad * 4 + r;
                if (m == 0) as2[row] = acc[r];
                else if (m == 1) ad2[row] = acc[r];
            }
        }
    }
}

// ---------------- layer-2 seg aggregation + fused classifier head -----------
// 16 nodes/block, single staging pass, 4 nodes per wave.
__global__ __launch_bounds__(256) void k_seg2f(
    const int* __restrict__ rp, const uchar* __restrict__ rcnt,
    const int* __restrict__ col,
    const float* __restrict__ as2, const float* __restrict__ ad2,
    const ushort* __restrict__ h2, const float* __restrict__ b2,
    const float* __restrict__ Wc, const float* __restrict__ bc,
    float* __restrict__ out, int N)
{
    __shared__ float pS[CHE];
    __shared__ int colS[CHE];
    __shared__ uchar ndS[CHE];
    __shared__ int sRp[BN + 1];
    __shared__ float adS[BN];
    __shared__ float b2S[64];
    __shared__ float wcS[64];

    const int tid = threadIdx.x;
    const int n0 = blockIdx.x * BN;
    if (tid < 64) { b2S[tid] = b2[tid]; wcS[tid] = Wc[tid]; }
    if (tid < BN) { sRp[tid] = rp[n0 + tid]; adS[tid] = ad2[n0 + tid]; }
    if (tid == BN) sRp[BN] = rp[n0 + BN - 1] + (int)rcnt[n0 + BN - 1];
    __syncthreads();

    const int eb0 = sRp[0];
    const int cnt = min(sRp[BN] - eb0, CHE);
    for (int t = tid; t < cnt; t += 256) {
        int ge = eb0 + t;
        colS[t] = col[ge];
        int nd = 0;
        #pragma unroll
        for (int k = 1; k < BN; ++k) nd += (ge >= sRp[k]);
        ndS[t] = (uchar)nd;
    }
    __syncthreads();
    for (int t = tid; t < cnt; t += 256)
        pS[t] = __expf(lrelu(as2[colS[t]] + adS[ndS[t]]));
    __syncthreads();

    const int w = tid >> 6, lane = tid & 63;
    const int slot = lane >> 4, c4 = lane & 15;

    for (int nl = 0; nl < 4; ++nl) {
        const int nb = w * 4 + nl;
        const int myn = n0 + nb;
        const int s_n = sRp[nb] - eb0, e_n = sRp[nb + 1] - eb0;
        float den = 0.f;
        f32x4 accA = {0,0,0,0}, accB = {0,0,0,0};
        for (int i = s_n + lane; i < e_n; i += 64) den += pS[i];
        int i = s_n;
        for (; i + 7 < e_n; i += 8) {
            int lA = i + slot, lB = lA + 4;
            float pA = pS[lA], pB = pS[lB];
            ushort4 hA = *(const ushort4*)&h2[(size_t)colS[lA] * 64 + c4 * 4];
            ushort4 hB = *(const ushort4*)&h2[(size_t)colS[lB] * 64 + c4 * 4];
            accA[0] = fmaf(pA, bf2f(hA.x), accA[0]);
            accA[1] = fmaf(pA, bf2f(hA.y), accA[1]);
            accA[2] = fmaf(pA, bf2f(hA.z), accA[2]);
            accA[3] = fmaf(pA, bf2f(hA.w), accA[3]);
            accB[0] = fmaf(pB, bf2f(hB.x), accB[0]);
            accB[1] = fmaf(pB, bf2f(hB.y), accB[1]);
            accB[2] = fmaf(pB, bf2f(hB.z), accB[2]);
            accB[3] = fmaf(pB, bf2f(hB.w), accB[3]);
        }
        for (; i < e_n; i += 4) {
            int ii = i + slot;
            if (ii < e_n) {
                float p = pS[ii];
                ushort4 hv = *(const ushort4*)&h2[(size_t)colS[ii] * 64 + c4 * 4];
                accA[0] = fmaf(p, bf2f(hv.x), accA[0]);
                accA[1] = fmaf(p, bf2f(hv.y), accA[1]);
                accA[2] = fmaf(p, bf2f(hv.z), accA[2]);
                accA[3] = fmaf(p, bf2f(hv.w), accA[3]);
            }
        }
        #pragma unroll
        for (int off = 32; off >= 1; off >>= 1) den += __shfl_xor(den, off);
        #pragma unroll
        for (int j = 0; j < 4; ++j) {
            accA[j] += accB[j];
            accA[j] += __shfl_xor(accA[j], 16);
            accA[j] += __shfl_xor(accA[j], 32);
        }
        if (slot == 0) {
            float inv = 1.f / (den + 1e-16f);
            float t2 = 0.f;
            #pragma unroll
            for (int j = 0; j < 4; ++j)
                t2 += relu_np(accA[j] * inv + b2S[c4 * 4 + j]) * wcS[c4 * 4 + j];
            t2 += __shfl_xor(t2, 1);
            t2 += __shfl_xor(t2, 2);
            t2 += __shfl_xor(t2, 4);
            t2 += __shfl_xor(t2, 8);
            if (c4 == 0) out[myn] = t2 + bc[0];
        }
    }
}

extern "C" void kernel_launch(void* const* d_in, const int* in_sizes, int n_in,
                              void* d_out, int out_size, void* d_ws, size_t ws_size,
                              hipStream_t stream)
{
    const float* x   = (const float*)d_in[0];
    const int*   ei  = (const int*)d_in[1];
    const float* W1  = (const float*)d_in[2];
    const float* aS1 = (const float*)d_in[3];
    const float* aD1 = (const float*)d_in[4];
    const float* b1  = (const float*)d_in[5];
    const float* W2  = (const float*)d_in[6];
    const float* aS2 = (const float*)d_in[7];
    const float* aD2 = (const float*)d_in[8];
    const float* b2  = (const float*)d_in[9];
    const float* Wc  = (const float*)d_in[10];
    const float* bc  = (const float*)d_in[11];
    float* out = (float*)d_out;

    const int N = NN;
    const int E = EE;
    const int* src = ei;
    const int* dst = ei + E;

    // ---- workspace layout (~36 MB) ----
    ushort* h1   = (ushort*)d_ws;                     // [N*64] bf16  12.8MB
    ushort* h2   = h1 + (size_t)N * 64;               // [N*64] bf16  12.8MB
    float*  as1  = (float*)(h2 + (size_t)N * 64);     // [4N]
    float*  ad1  = as1 + (size_t)N * 4;               // [4N]
    float*  as2  = ad1 + (size_t)N * 4;               // [N]
    float*  ad2  = as2 + (size_t)N;                   // [N]
    ushort* wExt = (ushort*)(ad2 + (size_t)N);        // [80*64] bf16 10KB
    int* row_ptr = (int*)(wExt + 80 * 64);            // [N]
    uchar* rcnt  = (uchar*)(row_ptr + N);             // [N] bytes
    int* gcur    = (int*)(rcnt + ((N + 3) & ~3));     // [NBK]
    int* col     = gcur + NBK;                        // [NBK*CAP] 8MB arena
    int* pairs   = (int*)h2;                          // aliases h2 (dead by seg1f)

    // ---- CSR build + W2ext prep ----
    k_init<<<1, 256, 0, stream>>>(gcur, W2, aS2, aD2, wExt);
    k_part<<<NT, 256, 0, stream>>>(src, dst, gcur, pairs, E);
    k_bucket<<<NBK, 256, 0, stream>>>(gcur, pairs, row_ptr, rcnt, col, N);

    // ---- layer 1 GEMM ----
    k_gemm1<<<782, 256, 0, stream>>>(x, W1, aS1, aD1, h1, as1, ad1, N);

    // ---- layer 1 aggregation + fused layer 2 GEMM ----
    k_seg1f<<<N / BN, 256, 0, stream>>>(row_ptr, rcnt, col, as1, ad1, h1, b1,
                                        wExt, h2, as2, ad2, N);

    // ---- layer 2 aggregation + fused classifier ----
    k_seg2f<<<N / BN, 256, 0, stream>>>(row_ptr, rcnt, col, as2, ad2, h2,
                                        b2, Wc, bc, out, N);
}

// Round 2
// 284.476 us; speedup vs baseline: 1.1050x; 1.0279x over previous
//
#include <hip/hip_runtime.h>
#include <hip/hip_bf16.h>

// ============================================================================
// GAT 2-layer forward, round 16.
// r15 post-mortem: seg1f top at 67.4us, 1.87TB/s vs 2.4TB/s random-fill
// ceiling, occupancy 51.6% — LDS 25.6KB -> 6 blocks/CU is the limiter, and
// 11.5KB of that is wS staging of the 10KB L2-hot W2ext table that is read
// once per block. Change: drop wS entirely; MFMA epilogue loads B fragments
// directly from global wExt (L2-resident) -> LDS ~13.9KB -> 8 blocks/CU
// (wave cap). __launch_bounds__(256,8) on both seg kernels. Numerics
// unchanged (same bf16 values, same MFMA).
// Facts: fp32 in/out, int32 edge_index, N=100000 E=1600000, bf16 h.
// ============================================================================

typedef __hip_bfloat16 bf16;
typedef unsigned short ushort;
typedef unsigned char uchar;
typedef __attribute__((ext_vector_type(8))) short short8;
typedef __attribute__((ext_vector_type(4))) float f32x4;

#define NN 100000
#define EE 1600000
#define BKB 9
#define BKN (1 << BKB)
#define NBK ((NN + BKN - 1) >> BKB)   // 196
#define CAP 10240                     // arena slots per bucket (max ~8.5K)
#define TILE 4096
#define EPT 16
#define NT ((EE + TILE - 1) / TILE)
#define BN 16                         // nodes per seg block (16 | 512 bucket)
#define CHE 512                       // max edges/block: mean 256, +16 sigma

__device__ __forceinline__ float relu_np(float v) { return (v < 0.f) ? 0.f : v; }
__device__ __forceinline__ float lrelu(float v) { return v > 0.f ? v : 0.2f * v; }
__device__ __forceinline__ ushort f2bf(float f) {
    __hip_bfloat16 h = __float2bfloat16(f);
    return *reinterpret_cast<ushort*>(&h);
}
__device__ __forceinline__ float bf2f(ushort u) {
    unsigned int x = ((unsigned int)u) << 16;
    return __uint_as_float(x);
}

// ---- init arena cursors + build W2ext^T bf16 [80][64] ----------------------
// n<64: W2 col n; n==64: W2 @ aS2; n==65: W2 @ aD2; n>=66: zero pad.
__global__ __launch_bounds__(256) void k_init(
    int* __restrict__ gcur, const float* __restrict__ W2,
    const float* __restrict__ aS2, const float* __restrict__ aD2,
    ushort* __restrict__ wExt)
{
    const int tid = threadIdx.x;
    if (tid < NBK) gcur[tid] = tid * CAP;
    for (int i = tid; i < 80 * 64; i += 256) {
        int n = i >> 6, k = i & 63;
        float v = 0.f;
        if (n < 64) {
            v = W2[k * 64 + n];
        } else if (n == 64) {
            for (int c = 0; c < 64; ++c) v = fmaf(W2[k * 64 + c], aS2[c], v);
        } else if (n == 65) {
            for (int c = 0; c < 64; ++c) v = fmaf(W2[k * 64 + c], aD2[c], v);
        }
        wExt[i] = f2bf(v);
    }
}

// ---- partition into per-bucket arenas (block-aggregated writes) ------------
__global__ __launch_bounds__(256) void k_part(
    const int* __restrict__ src, const int* __restrict__ dst,
    int* __restrict__ gcur, int* __restrict__ pairs, int E)
{
    __shared__ int lh[NBK];
    __shared__ int lbase[NBK];
    const int tid = threadIdx.x;
    for (int i = tid; i < NBK; i += 256) lh[i] = 0;
    __syncthreads();
    const int e0 = blockIdx.x * TILE;
    int pk[EPT], bk[EPT], rv[EPT];
    #pragma unroll
    for (int j = 0; j < EPT; ++j) {
        int e = e0 + j * 256 + tid;
        if (e < E) {
            int d = dst[e];
            bk[j] = d >> BKB;
            pk[j] = src[e] | ((d & (BKN - 1)) << 17);
            rv[j] = atomicAdd(&lh[bk[j]], 1);
        }
    }
    __syncthreads();
    for (int i = tid; i < NBK; i += 256)
        lbase[i] = lh[i] ? atomicAdd(&gcur[i], lh[i]) : 0;
    __syncthreads();
    #pragma unroll
    for (int j = 0; j < EPT; ++j) {
        int e = e0 + j * 256 + tid;
        if (e < E) pairs[lbase[bk[j]] + rv[j]] = pk[j];
    }
}

// ---- per-bucket: node hist + scan -> row_ptr + rcnt; scatter col -----------
__global__ __launch_bounds__(256) void k_bucket(
    const int* __restrict__ gcur, const int* __restrict__ pairs,
    int* __restrict__ row_ptr, uchar* __restrict__ rcnt,
    int* __restrict__ col, int N)
{
    __shared__ int hist[BKN];
    __shared__ int sP[256];
    const int b = blockIdx.x;
    const int n0 = b << BKB;
    const int tid = threadIdx.x;
    const int base = b * CAP, endE = gcur[b];
    for (int i = tid; i < BKN; i += 256) hist[i] = 0;
    __syncthreads();
    for (int i = base + tid; i < endE; i += 256)
        atomicAdd(&hist[pairs[i] >> 17], 1);
    __syncthreads();
    int a0 = hist[2 * tid], a1 = hist[2 * tid + 1];
    int tot = a0 + a1;
    sP[tid] = tot;
    __syncthreads();
    for (int off = 1; off < 256; off <<= 1) {
        int t = (tid >= off) ? sP[tid - off] : 0;
        __syncthreads();
        sP[tid] += t;
        __syncthreads();
    }
    const int excl = sP[tid] - tot;
    const int c0 = base + excl;
    hist[2 * tid] = c0;
    hist[2 * tid + 1] = c0 + a0;
    if (n0 + 2 * tid < N) {
        row_ptr[n0 + 2 * tid] = c0;
        rcnt[n0 + 2 * tid] = (uchar)a0;
    }
    if (n0 + 2 * tid + 1 < N) {
        row_ptr[n0 + 2 * tid + 1] = c0 + a0;
        rcnt[n0 + 2 * tid + 1] = (uchar)a1;
    }
    __syncthreads();
    for (int i = base + tid; i < endE; i += 256) {
        int pr = pairs[i];
        int p = atomicAdd(&hist[pr >> 17], 1);
        col[p] = pr & 0x1FFFF;
    }
}

// ---------------- GEMM1 (MFMA) with alpha as extra B columns -----------------
__global__ __launch_bounds__(256) void k_gemm1(
    const float* __restrict__ x, const float* __restrict__ W1,
    const float* __restrict__ aS, const float* __restrict__ aD,
    ushort* __restrict__ h1, float* __restrict__ as1, float* __restrict__ ad1,
    int N)
{
    __shared__ ushort wB[64 * 128];
    __shared__ ushort wE[16 * 128];
    const int tid = threadIdx.x;
    for (int i = tid; i < 128 * 64; i += 256) {
        int k = i >> 6, n = i & 63;
        wB[n * 128 + k] = f2bf(W1[i]);
    }
    for (int i = tid; i < 128 * 16; i += 256) {
        int k = i >> 4, j = i & 15;
        float v = 0.f;
        if (j < 8) {
            int h = j & 3;
            const float* av = (j < 4) ? aS : aD;
            for (int c = 0; c < 16; ++c)
                v = fmaf(W1[k * 64 + h * 16 + c], av[h * 16 + c], v);
        }
        wE[j * 128 + k] = f2bf(v);
    }
    __syncthreads();
    const int w = tid >> 6, lane = tid & 63;
    const int m = lane & 15, quad = lane >> 4;
    const int ntiles = N >> 4;
    for (int tile = blockIdx.x * 4 + w; tile < ntiles; tile += gridDim.x * 4) {
        const int row0 = tile << 4;
        f32x4 acc[4] = {f32x4{0,0,0,0}, f32x4{0,0,0,0},
                        f32x4{0,0,0,0}, f32x4{0,0,0,0}};
        f32x4 acc5 = {0, 0, 0, 0};
        const float* xp = x + (size_t)(row0 + m) * 128 + quad * 8;
        #pragma unroll
        for (int ks = 0; ks < 128; ks += 32) {
            f32x4 x0 = *(const f32x4*)(xp + ks);
            f32x4 x1 = *(const f32x4*)(xp + ks + 4);
            short8 a;
            #pragma unroll
            for (int j = 0; j < 4; ++j) a[j] = (short)f2bf(x0[j]);
            #pragma unroll
            for (int j = 0; j < 4; ++j) a[4 + j] = (short)f2bf(x1[j]);
            #pragma unroll
            for (int t = 0; t < 4; ++t) {
                short8 b = *(const short8*)&wB[(t * 16 + m) * 128 + ks + quad * 8];
                acc[t] = __builtin_amdgcn_mfma_f32_16x16x32_bf16(a, b, acc[t], 0, 0, 0);
            }
            short8 b5 = *(const short8*)&wE[m * 128 + ks + quad * 8];
            acc5 = __builtin_amdgcn_mfma_f32_16x16x32_bf16(a, b5, acc5, 0, 0, 0);
        }
        #pragma unroll
        for (int t = 0; t < 4; ++t)
            #pragma unroll
            for (int r = 0; r < 4; ++r)
                h1[(size_t)(row0 + quad * 4 + r) * 64 + t * 16 + m] = f2bf(acc[t][r]);
        #pragma unroll
        for (int r = 0; r < 4; ++r) {
            int row = row0 + quad * 4 + r;
            if (m < 4) as1[row * 4 + m] = acc5[r];
            else if (m < 8) ad1[row * 4 + (m - 4)] = acc5[r];
        }
    }
}

// ---------------- layer-1 seg aggregation + fused layer-2 GEMM ---------------
// 16 nodes/block, single staging pass. Per wave: 4 sequential nodes.
// Epilogue: z=relu(acc/den+b1) -> LDS bf16 [16][72-pad]; 10 MFMAs compute
// h2 = z @ W2ext (16x64x80); B fragments read DIRECTLY from global wExt
// (10KB, L2-hot) — no LDS staging, keeps block LDS ~13.9KB -> 8 blocks/CU.
__global__ __launch_bounds__(256, 8) void k_seg1f(
    const int* __restrict__ rp, const uchar* __restrict__ rcnt,
    const int* __restrict__ col,
    const float* __restrict__ as1, const float* __restrict__ ad1,
    const ushort* __restrict__ h1, const float* __restrict__ b1,
    const ushort* __restrict__ wExt,
    ushort* __restrict__ h2, float* __restrict__ as2, float* __restrict__ ad2,
    int N)
{
    __shared__ __align__(16) ushort zS[BN * 72];   // z bf16, rows padded 64->72
    __shared__ float pS[CHE * 4];
    __shared__ int colS[CHE];
    __shared__ uchar ndS[CHE];
    __shared__ int sRp[BN + 1];
    __shared__ float bS[64];
    __shared__ float adS[BN * 4];

    const int tid = threadIdx.x;
    const int n0 = blockIdx.x * BN;

    if (tid < 64) bS[tid] = b1[tid];
    if (tid < BN * 4) adS[tid] = ad1[(size_t)n0 * 4 + tid];
    if (tid < BN) sRp[tid] = rp[n0 + tid];
    if (tid == BN) sRp[BN] = rp[n0 + BN - 1] + (int)rcnt[n0 + BN - 1];
    __syncthreads();

    const int eb0 = sRp[0];
    const int cnt = min(sRp[BN] - eb0, CHE);       // mean 256, never near 512

    for (int t = tid; t < cnt; t += 256) {
        int ge = eb0 + t;
        colS[t] = col[ge];
        int nd = 0;
        #pragma unroll
        for (int k = 1; k < BN; ++k) nd += (ge >= sRp[k]);
        ndS[t] = (uchar)nd;
    }
    __syncthreads();
    for (int t = tid; t < cnt * 4; t += 256) {
        int e = t >> 2, hh = t & 3;
        float v = as1[(size_t)colS[e] * 4 + hh] + adS[ndS[e] * 4 + hh];
        pS[t] = __expf(lrelu(v));
    }
    __syncthreads();

    const int w = tid >> 6, lane = tid & 63;
    const int slot = lane >> 4, c4 = lane & 15, head = c4 >> 2;
    const int uid = slot * 4 + (c4 & 3);

    for (int nl = 0; nl < 4; ++nl) {
        const int nb = w * 4 + nl;
        const int s_n = sRp[nb] - eb0, e_n = sRp[nb + 1] - eb0;
        float den = 0.f;
        f32x4 accA = {0,0,0,0}, accB = {0,0,0,0};
        for (int i = s_n + uid; i < e_n; i += 16) den += pS[i * 4 + head];
        int i = s_n;
        for (; i + 7 < e_n; i += 8) {
            int lA = i + slot, lB = lA + 4;
            float pA = pS[lA * 4 + head], pB = pS[lB * 4 + head];
            ushort4 hA = *(const ushort4*)&h1[(size_t)colS[lA] * 64 + c4 * 4];
            ushort4 hB = *(const ushort4*)&h1[(size_t)colS[lB] * 64 + c4 * 4];
            accA[0] = fmaf(pA, bf2f(hA.x), accA[0]);
            accA[1] = fmaf(pA, bf2f(hA.y), accA[1]);
            accA[2] = fmaf(pA, bf2f(hA.z), accA[2]);
            accA[3] = fmaf(pA, bf2f(hA.w), accA[3]);
            accB[0] = fmaf(pB, bf2f(hB.x), accB[0]);
            accB[1] = fmaf(pB, bf2f(hB.y), accB[1]);
            accB[2] = fmaf(pB, bf2f(hB.z), accB[2]);
            accB[3] = fmaf(pB, bf2f(hB.w), accB[3]);
        }
        for (; i < e_n; i += 4) {
            int ii = i + slot;
            if (ii < e_n) {
                float p = pS[ii * 4 + head];
                ushort4 hv = *(const ushort4*)&h1[(size_t)colS[ii] * 64 + c4 * 4];
                accA[0] = fmaf(p, bf2f(hv.x), accA[0]);
                accA[1] = fmaf(p, bf2f(hv.y), accA[1]);
                accA[2] = fmaf(p, bf2f(hv.z), accA[2]);
                accA[3] = fmaf(p, bf2f(hv.w), accA[3]);
            }
        }
        den += __shfl_xor(den, 1);
        den += __shfl_xor(den, 2);
        den += __shfl_xor(den, 16);
        den += __shfl_xor(den, 32);
        #pragma unroll
        for (int j = 0; j < 4; ++j) {
            accA[j] += accB[j];
            accA[j] += __shfl_xor(accA[j], 16);
            accA[j] += __shfl_xor(accA[j], 32);
        }
        if (slot == 0) {
            float inv = 1.f / (den + 1e-16f);
            ushort4 zv;
            zv.x = f2bf(relu_np(accA[0] * inv + bS[c4 * 4 + 0]));
            zv.y = f2bf(relu_np(accA[1] * inv + bS[c4 * 4 + 1]));
            zv.z = f2bf(relu_np(accA[2] * inv + bS[c4 * 4 + 2]));
            zv.w = f2bf(relu_np(accA[3] * inv + bS[c4 * 4 + 3]));
            *(ushort4*)&zS[nb * 72 + c4 * 4] = zv;
        }
    }
    __syncthreads();

    // ---- fused gemm2 epilogue: 5 n-tiles over 4 waves (wave0 takes ext) ----
    // B fragments straight from global wExt [80][64] (L2-hot, 16B aligned).
    const int m = c4, quad = slot;
    for (int t = w; t < 5; t += 4) {
        f32x4 acc = {0, 0, 0, 0};
        #pragma unroll
        for (int ks = 0; ks < 64; ks += 32) {
            short8 a = *(const short8*)&zS[m * 72 + ks + quad * 8];
            short8 b = *(const short8*)&wExt[(t * 16 + m) * 64 + ks + quad * 8];
            acc = __builtin_amdgcn_mfma_f32_16x16x32_bf16(a, b, acc, 0, 0, 0);
        }
        if (t < 4) {
            #pragma unroll
            for (int r = 0; r < 4; ++r)
                h2[(size_t)(n0 + quad * 4 + r) * 64 + t * 16 + m] = f2bf(acc[r]);
        } else {
            #pragma unroll
            for (int r = 0; r < 4; ++r) {
                int row = n0 + quad * 4 + r;
                if (m == 0) as2[row] = acc[r];
                else if (m == 1) ad2[row] = acc[r];
            }
        }
    }
}

// ---------------- layer-2 seg aggregation + fused classifier head -----------
// 16 nodes/block, single staging pass, 4 nodes per wave.
__global__ __launch_bounds__(256, 8) void k_seg2f(
    const int* __restrict__ rp, const uchar* __restrict__ rcnt,
    const int* __restrict__ col,
    const float* __restrict__ as2, const float* __restrict__ ad2,
    const ushort* __restrict__ h2, const float* __restrict__ b2,
    const float* __restrict__ Wc, const float* __restrict__ bc,
    float* __restrict__ out, int N)
{
    __shared__ float pS[CHE];
    __shared__ int colS[CHE];
    __shared__ uchar ndS[CHE];
    __shared__ int sRp[BN + 1];
    __shared__ float adS[BN];
    __shared__ float b2S[64];
    __shared__ float wcS[64];

    const int tid = threadIdx.x;
    const int n0 = blockIdx.x * BN;
    if (tid < 64) { b2S[tid] = b2[tid]; wcS[tid] = Wc[tid]; }
    if (tid < BN) { sRp[tid] = rp[n0 + tid]; adS[tid] = ad2[n0 + tid]; }
    if (tid == BN) sRp[BN] = rp[n0 + BN - 1] + (int)rcnt[n0 + BN - 1];
    __syncthreads();

    const int eb0 = sRp[0];
    const int cnt = min(sRp[BN] - eb0, CHE);
    for (int t = tid; t < cnt; t += 256) {
        int ge = eb0 + t;
        colS[t] = col[ge];
        int nd = 0;
        #pragma unroll
        for (int k = 1; k < BN; ++k) nd += (ge >= sRp[k]);
        ndS[t] = (uchar)nd;
    }
    __syncthreads();
    for (int t = tid; t < cnt; t += 256)
        pS[t] = __expf(lrelu(as2[colS[t]] + adS[ndS[t]]));
    __syncthreads();

    const int w = tid >> 6, lane = tid & 63;
    const int slot = lane >> 4, c4 = lane & 15;

    for (int nl = 0; nl < 4; ++nl) {
        const int nb = w * 4 + nl;
        const int myn = n0 + nb;
        const int s_n = sRp[nb] - eb0, e_n = sRp[nb + 1] - eb0;
        float den = 0.f;
        f32x4 accA = {0,0,0,0}, accB = {0,0,0,0};
        for (int i = s_n + lane; i < e_n; i += 64) den += pS[i];
        int i = s_n;
        for (; i + 7 < e_n; i += 8) {
            int lA = i + slot, lB = lA + 4;
            float pA = pS[lA], pB = pS[lB];
            ushort4 hA = *(const ushort4*)&h2[(size_t)colS[lA] * 64 + c4 * 4];
            ushort4 hB = *(const ushort4*)&h2[(size_t)colS[lB] * 64 + c4 * 4];
            accA[0] = fmaf(pA, bf2f(hA.x), accA[0]);
            accA[1] = fmaf(pA, bf2f(hA.y), accA[1]);
            accA[2] = fmaf(pA, bf2f(hA.z), accA[2]);
            accA[3] = fmaf(pA, bf2f(hA.w), accA[3]);
            accB[0] = fmaf(pB, bf2f(hB.x), accB[0]);
            accB[1] = fmaf(pB, bf2f(hB.y), accB[1]);
            accB[2] = fmaf(pB, bf2f(hB.z), accB[2]);
            accB[3] = fmaf(pB, bf2f(hB.w), accB[3]);
        }
        for (; i < e_n; i += 4) {
            int ii = i + slot;
            if (ii < e_n) {
                float p = pS[ii];
                ushort4 hv = *(const ushort4*)&h2[(size_t)colS[ii] * 64 + c4 * 4];
                accA[0] = fmaf(p, bf2f(hv.x), accA[0]);
                accA[1] = fmaf(p, bf2f(hv.y), accA[1]);
                accA[2] = fmaf(p, bf2f(hv.z), accA[2]);
                accA[3] = fmaf(p, bf2f(hv.w), accA[3]);
            }
        }
        #pragma unroll
        for (int off = 32; off >= 1; off >>= 1) den += __shfl_xor(den, off);
        #pragma unroll
        for (int j = 0; j < 4; ++j) {
            accA[j] += accB[j];
            accA[j] += __shfl_xor(accA[j], 16);
            accA[j] += __shfl_xor(accA[j], 32);
        }
        if (slot == 0) {
            float inv = 1.f / (den + 1e-16f);
            float t2 = 0.f;
            #pragma unroll
            for (int j = 0; j < 4; ++j)
                t2 += relu_np(accA[j] * inv + b2S[c4 * 4 + j]) * wcS[c4 * 4 + j];
            t2 += __shfl_xor(t2, 1);
            t2 += __shfl_xor(t2, 2);
            t2 += __shfl_xor(t2, 4);
            t2 += __shfl_xor(t2, 8);
            if (c4 == 0) out[myn] = t2 + bc[0];
        }
    }
}

extern "C" void kernel_launch(void* const* d_in, const int* in_sizes, int n_in,
                              void* d_out, int out_size, void* d_ws, size_t ws_size,
                              hipStream_t stream)
{
    const float* x   = (const float*)d_in[0];
    const int*   ei  = (const int*)d_in[1];
    const float* W1  = (const float*)d_in[2];
    const float* aS1 = (const float*)d_in[3];
    const float* aD1 = (const float*)d_in[4];
    const float* b1  = (const float*)d_in[5];
    const float* W2  = (const float*)d_in[6];
    const float* aS2 = (const float*)d_in[7];
    const float* aD2 = (const float*)d_in[8];
    const float* b2  = (const float*)d_in[9];
    const float* Wc  = (const float*)d_in[10];
    const float* bc  = (const float*)d_in[11];
    float* out = (float*)d_out;

    const int N = NN;
    const int E = EE;
    const int* src = ei;
    const int* dst = ei + E;

    // ---- workspace layout (~36 MB) ----
    ushort* h1   = (ushort*)d_ws;                     // [N*64] bf16  12.8MB
    ushort* h2   = h1 + (size_t)N * 64;               // [N*64] bf16  12.8MB
    float*  as1  = (float*)(h2 + (size_t)N * 64);     // [4N]
    float*  ad1  = as1 + (size_t)N * 4;               // [4N]
    float*  as2  = ad1 + (size_t)N * 4;               // [N]
    float*  ad2  = as2 + (size_t)N;                   // [N]
    ushort* wExt = (ushort*)(ad2 + (size_t)N);        // [80*64] bf16 10KB
    int* row_ptr = (int*)(wExt + 80 * 64);            // [N]
    uchar* rcnt  = (uchar*)(row_ptr + N);             // [N] bytes
    int* gcur    = (int*)(rcnt + ((N + 3) & ~3));     // [NBK]
    int* col     = gcur + NBK;                        // [NBK*CAP] 8MB arena
    int* pairs   = (int*)h2;                          // aliases h2 (dead by seg1f)

    // ---- CSR build + W2ext prep ----
    k_init<<<1, 256, 0, stream>>>(gcur, W2, aS2, aD2, wExt);
    k_part<<<NT, 256, 0, stream>>>(src, dst, gcur, pairs, E);
    k_bucket<<<NBK, 256, 0, stream>>>(gcur, pairs, row_ptr, rcnt, col, N);

    // ---- layer 1 GEMM ----
    k_gemm1<<<782, 256, 0, stream>>>(x, W1, aS1, aD1, h1, as1, ad1, N);

    // ---- layer 1 aggregation + fused layer 2 GEMM ----
    k_seg1f<<<N / BN, 256, 0, stream>>>(row_ptr, rcnt, col, as1, ad1, h1, b1,
                                        wExt, h2, as2, ad2, N);

    // ---- layer 2 aggregation + fused classifier ----
    k_seg2f<<<N / BN, 256, 0, stream>>>(row_ptr, rcnt, col, as2, ad2, h2,
                                        b2, Wc, bc, out, N);
}

// Round 4
// 267.837 us; speedup vs baseline: 1.1736x; 1.0621x over previous
//
#include <hip/hip_runtime.h>
#include <hip/hip_bf16.h>

// ============================================================================
// GAT 2-layer forward, round 18 (= r17 resubmitted; r17 bench was an infra
// container failure, no measurement taken).
// r16 post-mortem: seg1f at 2.14TB/s = 89% of the ~2.4TB/s L3->L2 random-fill
// ceiling; FETCH 104MB == 8 XCDs x 12.8MB h1 compulsory floor + streams —
// bytes are minimal. VALUBusy 55% says the limiter is per-node reduction
// overhead: 4 sequential nodes/wave, ~2 gather iters/node, then ~10 shuffles.
// Change: one node per 16-lane slot-group. Lane owns 4 feature cols across
// ALL of its node's edges -> no acc/den shuffles at all; den folds into the
// gather; 4-edge unroll -> 4 loads in flight/lane (16/wave). seg2f same
// (keeps only the 4-shuffle classifier reduce). Numerics: fp32 sum-order
// change only.
// Facts: fp32 in/out, int32 edge_index, N=100000 E=1600000, bf16 h.
// ============================================================================

typedef __hip_bfloat16 bf16;
typedef unsigned short ushort;
typedef unsigned char uchar;
typedef __attribute__((ext_vector_type(8))) short short8;
typedef __attribute__((ext_vector_type(4))) float f32x4;

#define NN 100000
#define EE 1600000
#define BKB 9
#define BKN (1 << BKB)
#define NBK ((NN + BKN - 1) >> BKB)   // 196
#define CAP 10240                     // arena slots per bucket (max ~8.5K)
#define TILE 4096
#define EPT 16
#define NT ((EE + TILE - 1) / TILE)
#define BN 16                         // nodes per seg block (16 | 512 bucket)
#define CHE 512                       // max edges/block: mean 256, +16 sigma

__device__ __forceinline__ float relu_np(float v) { return (v < 0.f) ? 0.f : v; }
__device__ __forceinline__ float lrelu(float v) { return v > 0.f ? v : 0.2f * v; }
__device__ __forceinline__ ushort f2bf(float f) {
    __hip_bfloat16 h = __float2bfloat16(f);
    return *reinterpret_cast<ushort*>(&h);
}
__device__ __forceinline__ float bf2f(ushort u) {
    unsigned int x = ((unsigned int)u) << 16;
    return __uint_as_float(x);
}

// ---- init arena cursors + build W2ext^T bf16 [80][64] ----------------------
// n<64: W2 col n; n==64: W2 @ aS2; n==65: W2 @ aD2; n>=66: zero pad.
__global__ __launch_bounds__(256) void k_init(
    int* __restrict__ gcur, const float* __restrict__ W2,
    const float* __restrict__ aS2, const float* __restrict__ aD2,
    ushort* __restrict__ wExt)
{
    const int tid = threadIdx.x;
    if (tid < NBK) gcur[tid] = tid * CAP;
    for (int i = tid; i < 80 * 64; i += 256) {
        int n = i >> 6, k = i & 63;
        float v = 0.f;
        if (n < 64) {
            v = W2[k * 64 + n];
        } else if (n == 64) {
            for (int c = 0; c < 64; ++c) v = fmaf(W2[k * 64 + c], aS2[c], v);
        } else if (n == 65) {
            for (int c = 0; c < 64; ++c) v = fmaf(W2[k * 64 + c], aD2[c], v);
        }
        wExt[i] = f2bf(v);
    }
}

// ---- partition into per-bucket arenas (block-aggregated writes) ------------
__global__ __launch_bounds__(256) void k_part(
    const int* __restrict__ src, const int* __restrict__ dst,
    int* __restrict__ gcur, int* __restrict__ pairs, int E)
{
    __shared__ int lh[NBK];
    __shared__ int lbase[NBK];
    const int tid = threadIdx.x;
    for (int i = tid; i < NBK; i += 256) lh[i] = 0;
    __syncthreads();
    const int e0 = blockIdx.x * TILE;
    int pk[EPT], bk[EPT], rv[EPT];
    #pragma unroll
    for (int j = 0; j < EPT; ++j) {
        int e = e0 + j * 256 + tid;
        if (e < E) {
            int d = dst[e];
            bk[j] = d >> BKB;
            pk[j] = src[e] | ((d & (BKN - 1)) << 17);
            rv[j] = atomicAdd(&lh[bk[j]], 1);
        }
    }
    __syncthreads();
    for (int i = tid; i < NBK; i += 256)
        lbase[i] = lh[i] ? atomicAdd(&gcur[i], lh[i]) : 0;
    __syncthreads();
    #pragma unroll
    for (int j = 0; j < EPT; ++j) {
        int e = e0 + j * 256 + tid;
        if (e < E) pairs[lbase[bk[j]] + rv[j]] = pk[j];
    }
}

// ---- per-bucket: node hist + scan -> row_ptr + rcnt; scatter col -----------
__global__ __launch_bounds__(256) void k_bucket(
    const int* __restrict__ gcur, const int* __restrict__ pairs,
    int* __restrict__ row_ptr, uchar* __restrict__ rcnt,
    int* __restrict__ col, int N)
{
    __shared__ int hist[BKN];
    __shared__ int sP[256];
    const int b = blockIdx.x;
    const int n0 = b << BKB;
    const int tid = threadIdx.x;
    const int base = b * CAP, endE = gcur[b];
    for (int i = tid; i < BKN; i += 256) hist[i] = 0;
    __syncthreads();
    for (int i = base + tid; i < endE; i += 256)
        atomicAdd(&hist[pairs[i] >> 17], 1);
    __syncthreads();
    int a0 = hist[2 * tid], a1 = hist[2 * tid + 1];
    int tot = a0 + a1;
    sP[tid] = tot;
    __syncthreads();
    for (int off = 1; off < 256; off <<= 1) {
        int t = (tid >= off) ? sP[tid - off] : 0;
        __syncthreads();
        sP[tid] += t;
        __syncthreads();
    }
    const int excl = sP[tid] - tot;
    const int c0 = base + excl;
    hist[2 * tid] = c0;
    hist[2 * tid + 1] = c0 + a0;
    if (n0 + 2 * tid < N) {
        row_ptr[n0 + 2 * tid] = c0;
        rcnt[n0 + 2 * tid] = (uchar)a0;
    }
    if (n0 + 2 * tid + 1 < N) {
        row_ptr[n0 + 2 * tid + 1] = c0 + a0;
        rcnt[n0 + 2 * tid + 1] = (uchar)a1;
    }
    __syncthreads();
    for (int i = base + tid; i < endE; i += 256) {
        int pr = pairs[i];
        int p = atomicAdd(&hist[pr >> 17], 1);
        col[p] = pr & 0x1FFFF;
    }
}

// ---------------- GEMM1 (MFMA) with alpha as extra B columns -----------------
__global__ __launch_bounds__(256) void k_gemm1(
    const float* __restrict__ x, const float* __restrict__ W1,
    const float* __restrict__ aS, const float* __restrict__ aD,
    ushort* __restrict__ h1, float* __restrict__ as1, float* __restrict__ ad1,
    int N)
{
    __shared__ ushort wB[64 * 128];
    __shared__ ushort wE[16 * 128];
    const int tid = threadIdx.x;
    for (int i = tid; i < 128 * 64; i += 256) {
        int k = i >> 6, n = i & 63;
        wB[n * 128 + k] = f2bf(W1[i]);
    }
    for (int i = tid; i < 128 * 16; i += 256) {
        int k = i >> 4, j = i & 15;
        float v = 0.f;
        if (j < 8) {
            int h = j & 3;
            const float* av = (j < 4) ? aS : aD;
            for (int c = 0; c < 16; ++c)
                v = fmaf(W1[k * 64 + h * 16 + c], av[h * 16 + c], v);
        }
        wE[j * 128 + k] = f2bf(v);
    }
    __syncthreads();
    const int w = tid >> 6, lane = tid & 63;
    const int m = lane & 15, quad = lane >> 4;
    const int ntiles = N >> 4;
    for (int tile = blockIdx.x * 4 + w; tile < ntiles; tile += gridDim.x * 4) {
        const int row0 = tile << 4;
        f32x4 acc[4] = {f32x4{0,0,0,0}, f32x4{0,0,0,0},
                        f32x4{0,0,0,0}, f32x4{0,0,0,0}};
        f32x4 acc5 = {0, 0, 0, 0};
        const float* xp = x + (size_t)(row0 + m) * 128 + quad * 8;
        #pragma unroll
        for (int ks = 0; ks < 128; ks += 32) {
            f32x4 x0 = *(const f32x4*)(xp + ks);
            f32x4 x1 = *(const f32x4*)(xp + ks + 4);
            short8 a;
            #pragma unroll
            for (int j = 0; j < 4; ++j) a[j] = (short)f2bf(x0[j]);
            #pragma unroll
            for (int j = 0; j < 4; ++j) a[4 + j] = (short)f2bf(x1[j]);
            #pragma unroll
            for (int t = 0; t < 4; ++t) {
                short8 b = *(const short8*)&wB[(t * 16 + m) * 128 + ks + quad * 8];
                acc[t] = __builtin_amdgcn_mfma_f32_16x16x32_bf16(a, b, acc[t], 0, 0, 0);
            }
            short8 b5 = *(const short8*)&wE[m * 128 + ks + quad * 8];
            acc5 = __builtin_amdgcn_mfma_f32_16x16x32_bf16(a, b5, acc5, 0, 0, 0);
        }
        #pragma unroll
        for (int t = 0; t < 4; ++t)
            #pragma unroll
            for (int r = 0; r < 4; ++r)
                h1[(size_t)(row0 + quad * 4 + r) * 64 + t * 16 + m] = f2bf(acc[t][r]);
        #pragma unroll
        for (int r = 0; r < 4; ++r) {
            int row = row0 + quad * 4 + r;
            if (m < 4) as1[row * 4 + m] = acc5[r];
            else if (m < 8) ad1[row * 4 + (m - 4)] = acc5[r];
        }
    }
}

// ---------------- layer-1 seg aggregation + fused layer-2 GEMM ---------------
// 16 nodes/block = 4 waves x 4 slot-groups; one node per 16-lane group.
// Lane owns feature cols c4*4..+3 across all its node's edges: no acc/den
// cross-lane reduction. 4-edge unroll -> 4 loads in flight per lane.
// Epilogue: z=relu(acc/den+b1) -> LDS bf16 [16][72]; 10 MFMAs, B from global
// wExt (L2-hot).
__global__ __launch_bounds__(256, 8) void k_seg1f(
    const int* __restrict__ rp, const uchar* __restrict__ rcnt,
    const int* __restrict__ col,
    const float* __restrict__ as1, const float* __restrict__ ad1,
    const ushort* __restrict__ h1, const float* __restrict__ b1,
    const ushort* __restrict__ wExt,
    ushort* __restrict__ h2, float* __restrict__ as2, float* __restrict__ ad2,
    int N)
{
    __shared__ __align__(16) ushort zS[BN * 72];   // z bf16, rows padded 64->72
    __shared__ float pS[CHE * 4];
    __shared__ int colS[CHE];
    __shared__ uchar ndS[CHE];
    __shared__ int sRp[BN + 1];
    __shared__ float bS[64];
    __shared__ float adS[BN * 4];

    const int tid = threadIdx.x;
    const int n0 = blockIdx.x * BN;

    if (tid < 64) bS[tid] = b1[tid];
    if (tid < BN * 4) adS[tid] = ad1[(size_t)n0 * 4 + tid];
    if (tid < BN) sRp[tid] = rp[n0 + tid];
    if (tid == BN) sRp[BN] = rp[n0 + BN - 1] + (int)rcnt[n0 + BN - 1];
    __syncthreads();

    const int eb0 = sRp[0];
    const int cnt = min(sRp[BN] - eb0, CHE);       // mean 256, never near 512

    for (int t = tid; t < cnt; t += 256) {
        int ge = eb0 + t;
        colS[t] = col[ge];
        int nd = 0;
        #pragma unroll
        for (int k = 1; k < BN; ++k) nd += (ge >= sRp[k]);
        ndS[t] = (uchar)nd;
    }
    __syncthreads();
    for (int t = tid; t < cnt * 4; t += 256) {
        int e = t >> 2, hh = t & 3;
        float v = as1[(size_t)colS[e] * 4 + hh] + adS[ndS[e] * 4 + hh];
        pS[t] = __expf(lrelu(v));
    }
    __syncthreads();

    const int w = tid >> 6, lane = tid & 63;
    const int g = lane >> 4, c4 = lane & 15, head = c4 >> 2;
    const int nb = w * 4 + g;
    const int s_n = sRp[nb] - eb0, e_n = sRp[nb + 1] - eb0;

    f32x4 acc = {0, 0, 0, 0};
    float den = 0.f;
    int i = s_n;
    for (; i + 3 < e_n; i += 4) {
        int cA = colS[i], cB = colS[i + 1], cC = colS[i + 2], cD = colS[i + 3];
        ushort4 hA = *(const ushort4*)&h1[(size_t)cA * 64 + c4 * 4];
        ushort4 hB = *(const ushort4*)&h1[(size_t)cB * 64 + c4 * 4];
        ushort4 hC = *(const ushort4*)&h1[(size_t)cC * 64 + c4 * 4];
        ushort4 hD = *(const ushort4*)&h1[(size_t)cD * 64 + c4 * 4];
        float pA = pS[(i + 0) * 4 + head], pB = pS[(i + 1) * 4 + head];
        float pC = pS[(i + 2) * 4 + head], pD = pS[(i + 3) * 4 + head];
        den += (pA + pB) + (pC + pD);
        acc[0] = fmaf(pA, bf2f(hA.x), acc[0]);
        acc[1] = fmaf(pA, bf2f(hA.y), acc[1]);
        acc[2] = fmaf(pA, bf2f(hA.z), acc[2]);
        acc[3] = fmaf(pA, bf2f(hA.w), acc[3]);
        acc[0] = fmaf(pB, bf2f(hB.x), acc[0]);
        acc[1] = fmaf(pB, bf2f(hB.y), acc[1]);
        acc[2] = fmaf(pB, bf2f(hB.z), acc[2]);
        acc[3] = fmaf(pB, bf2f(hB.w), acc[3]);
        acc[0] = fmaf(pC, bf2f(hC.x), acc[0]);
        acc[1] = fmaf(pC, bf2f(hC.y), acc[1]);
        acc[2] = fmaf(pC, bf2f(hC.z), acc[2]);
        acc[3] = fmaf(pC, bf2f(hC.w), acc[3]);
        acc[0] = fmaf(pD, bf2f(hD.x), acc[0]);
        acc[1] = fmaf(pD, bf2f(hD.y), acc[1]);
        acc[2] = fmaf(pD, bf2f(hD.z), acc[2]);
        acc[3] = fmaf(pD, bf2f(hD.w), acc[3]);
    }
    for (; i < e_n; ++i) {
        int cA = colS[i];
        ushort4 hA = *(const ushort4*)&h1[(size_t)cA * 64 + c4 * 4];
        float pA = pS[i * 4 + head];
        den += pA;
        acc[0] = fmaf(pA, bf2f(hA.x), acc[0]);
        acc[1] = fmaf(pA, bf2f(hA.y), acc[1]);
        acc[2] = fmaf(pA, bf2f(hA.z), acc[2]);
        acc[3] = fmaf(pA, bf2f(hA.w), acc[3]);
    }
    {
        float inv = 1.f / (den + 1e-16f);
        ushort4 zv;
        zv.x = f2bf(relu_np(acc[0] * inv + bS[c4 * 4 + 0]));
        zv.y = f2bf(relu_np(acc[1] * inv + bS[c4 * 4 + 1]));
        zv.z = f2bf(relu_np(acc[2] * inv + bS[c4 * 4 + 2]));
        zv.w = f2bf(relu_np(acc[3] * inv + bS[c4 * 4 + 3]));
        *(ushort4*)&zS[nb * 72 + c4 * 4] = zv;
    }
    __syncthreads();

    // ---- fused gemm2 epilogue: 5 n-tiles over 4 waves (wave0 takes ext) ----
    // B fragments straight from global wExt [80][64] (L2-hot, 16B aligned).
    const int m = c4, quad = g;
    for (int t = w; t < 5; t += 4) {
        f32x4 acct = {0, 0, 0, 0};
        #pragma unroll
        for (int ks = 0; ks < 64; ks += 32) {
            short8 a = *(const short8*)&zS[m * 72 + ks + quad * 8];
            short8 b = *(const short8*)&wExt[(t * 16 + m) * 64 + ks + quad * 8];
            acct = __builtin_amdgcn_mfma_f32_16x16x32_bf16(a, b, acct, 0, 0, 0);
        }
        if (t < 4) {
            #pragma unroll
            for (int r = 0; r < 4; ++r)
                h2[(size_t)(n0 + quad * 4 + r) * 64 + t * 16 + m] = f2bf(acct[r]);
        } else {
            #pragma unroll
            for (int r = 0; r < 4; ++r) {
                int row = n0 + quad * 4 + r;
                if (m == 0) as2[row] = acct[r];
                else if (m == 1) ad2[row] = acct[r];
            }
        }
    }
}

// ---------------- layer-2 seg aggregation + fused classifier head -----------
// Same one-node-per-16-lane-group structure; only the classifier dot product
// needs a cross-lane (4-shuffle) reduce.
__global__ __launch_bounds__(256, 8) void k_seg2f(
    const int* __restrict__ rp, const uchar* __restrict__ rcnt,
    const int* __restrict__ col,
    const float* __restrict__ as2, const float* __restrict__ ad2,
    const ushort* __restrict__ h2, const float* __restrict__ b2,
    const float* __restrict__ Wc, const float* __restrict__ bc,
    float* __restrict__ out, int N)
{
    __shared__ float pS[CHE];
    __shared__ int colS[CHE];
    __shared__ uchar ndS[CHE];
    __shared__ int sRp[BN + 1];
    __shared__ float adS[BN];
    __shared__ float b2S[64];
    __shared__ float wcS[64];

    const int tid = threadIdx.x;
    const int n0 = blockIdx.x * BN;
    if (tid < 64) { b2S[tid] = b2[tid]; wcS[tid] = Wc[tid]; }
    if (tid < BN) { sRp[tid] = rp[n0 + tid]; adS[tid] = ad2[n0 + tid]; }
    if (tid == BN) sRp[BN] = rp[n0 + BN - 1] + (int)rcnt[n0 + BN - 1];
    __syncthreads();

    const int eb0 = sRp[0];
    const int cnt = min(sRp[BN] - eb0, CHE);
    for (int t = tid; t < cnt; t += 256) {
        int ge = eb0 + t;
        colS[t] = col[ge];
        int nd = 0;
        #pragma unroll
        for (int k = 1; k < BN; ++k) nd += (ge >= sRp[k]);
        ndS[t] = (uchar)nd;
    }
    __syncthreads();
    for (int t = tid; t < cnt; t += 256)
        pS[t] = __expf(lrelu(as2[colS[t]] + adS[ndS[t]]));
    __syncthreads();

    const int w = tid >> 6, lane = tid & 63;
    const int g = lane >> 4, c4 = lane & 15;
    const int nb = w * 4 + g;
    const int myn = n0 + nb;
    const int s_n = sRp[nb] - eb0, e_n = sRp[nb + 1] - eb0;

    f32x4 acc = {0, 0, 0, 0};
    float den = 0.f;
    int i = s_n;
    for (; i + 3 < e_n; i += 4) {
        int cA = colS[i], cB = colS[i + 1], cC = colS[i + 2], cD = colS[i + 3];
        ushort4 hA = *(const ushort4*)&h2[(size_t)cA * 64 + c4 * 4];
        ushort4 hB = *(const ushort4*)&h2[(size_t)cB * 64 + c4 * 4];
        ushort4 hC = *(const ushort4*)&h2[(size_t)cC * 64 + c4 * 4];
        ushort4 hD = *(const ushort4*)&h2[(size_t)cD * 64 + c4 * 4];
        float pA = pS[i + 0], pB = pS[i + 1], pC = pS[i + 2], pD = pS[i + 3];
        den += (pA + pB) + (pC + pD);
        acc[0] = fmaf(pA, bf2f(hA.x), acc[0]);
        acc[1] = fmaf(pA, bf2f(hA.y), acc[1]);
        acc[2] = fmaf(pA, bf2f(hA.z), acc[2]);
        acc[3] = fmaf(pA, bf2f(hA.w), acc[3]);
        acc[0] = fmaf(pB, bf2f(hB.x), acc[0]);
        acc[1] = fmaf(pB, bf2f(hB.y), acc[1]);
        acc[2] = fmaf(pB, bf2f(hB.z), acc[2]);
        acc[3] = fmaf(pB, bf2f(hB.w), acc[3]);
        acc[0] = fmaf(pC, bf2f(hC.x), acc[0]);
        acc[1] = fmaf(pC, bf2f(hC.y), acc[1]);
        acc[2] = fmaf(pC, bf2f(hC.z), acc[2]);
        acc[3] = fmaf(pC, bf2f(hC.w), acc[3]);
        acc[0] = fmaf(pD, bf2f(hD.x), acc[0]);
        acc[1] = fmaf(pD, bf2f(hD.y), acc[1]);
        acc[2] = fmaf(pD, bf2f(hD.z), acc[2]);
        acc[3] = fmaf(pD, bf2f(hD.w), acc[3]);
    }
    for (; i < e_n; ++i) {
        int cA = colS[i];
        ushort4 hA = *(const ushort4*)&h2[(size_t)cA * 64 + c4 * 4];
        float pA = pS[i];
        den += pA;
        acc[0] = fmaf(pA, bf2f(hA.x), acc[0]);
        acc[1] = fmaf(pA, bf2f(hA.y), acc[1]);
        acc[2] = fmaf(pA, bf2f(hA.z), acc[2]);
        acc[3] = fmaf(pA, bf2f(hA.w), acc[3]);
    }

    float inv = 1.f / (den + 1e-16f);
    float t2 = 0.f;
    #pragma unroll
    for (int j = 0; j < 4; ++j)
        t2 += relu_np(acc[j] * inv + b2S[c4 * 4 + j]) * wcS[c4 * 4 + j];
    t2 += __shfl_xor(t2, 1);
    t2 += __shfl_xor(t2, 2);
    t2 += __shfl_xor(t2, 4);
    t2 += __shfl_xor(t2, 8);
    if (c4 == 0) out[myn] = t2 + bc[0];
}

extern "C" void kernel_launch(void* const* d_in, const int* in_sizes, int n_in,
                              void* d_out, int out_size, void* d_ws, size_t ws_size,
                              hipStream_t stream)
{
    const float* x   = (const float*)d_in[0];
    const int*   ei  = (const int*)d_in[1];
    const float* W1  = (const float*)d_in[2];
    const float* aS1 = (const float*)d_in[3];
    const float* aD1 = (const float*)d_in[4];
    const float* b1  = (const float*)d_in[5];
    const float* W2  = (const float*)d_in[6];
    const float* aS2 = (const float*)d_in[7];
    const float* aD2 = (const float*)d_in[8];
    const float* b2  = (const float*)d_in[9];
    const float* Wc  = (const float*)d_in[10];
    const float* bc  = (const float*)d_in[11];
    float* out = (float*)d_out;

    const int N = NN;
    const int E = EE;
    const int* src = ei;
    const int* dst = ei + E;

    // ---- workspace layout (~36 MB) ----
    ushort* h1   = (ushort*)d_ws;                     // [N*64] bf16  12.8MB
    ushort* h2   = h1 + (size_t)N * 64;               // [N*64] bf16  12.8MB
    float*  as1  = (float*)(h2 + (size_t)N * 64);     // [4N]
    float*  ad1  = as1 + (size_t)N * 4;               // [4N]
    float*  as2  = ad1 + (size_t)N * 4;               // [N]
    float*  ad2  = as2 + (size_t)N;                   // [N]
    ushort* wExt = (ushort*)(ad2 + (size_t)N);        // [80*64] bf16 10KB
    int* row_ptr = (int*)(wExt + 80 * 64);            // [N]
    uchar* rcnt  = (uchar*)(row_ptr + N);             // [N] bytes
    int* gcur    = (int*)(rcnt + ((N + 3) & ~3));     // [NBK]
    int* col     = gcur + NBK;                        // [NBK*CAP] 8MB arena
    int* pairs   = (int*)h2;                          // aliases h2 (dead by seg1f)

    // ---- CSR build + W2ext prep ----
    k_init<<<1, 256, 0, stream>>>(gcur, W2, aS2, aD2, wExt);
    k_part<<<NT, 256, 0, stream>>>(src, dst, gcur, pairs, E);
    k_bucket<<<NBK, 256, 0, stream>>>(gcur, pairs, row_ptr, rcnt, col, N);

    // ---- layer 1 GEMM ----
    k_gemm1<<<782, 256, 0, stream>>>(x, W1, aS1, aD1, h1, as1, ad1, N);

    // ---- layer 1 aggregation + fused layer 2 GEMM ----
    k_seg1f<<<N / BN, 256, 0, stream>>>(row_ptr, rcnt, col, as1, ad1, h1, b1,
                                        wExt, h2, as2, ad2, N);

    // ---- layer 2 aggregation + fused classifier ----
    k_seg2f<<<N / BN, 256, 0, stream>>>(row_ptr, rcnt, col, as2, ad2, h2,
                                        b2, Wc, bc, out, N);
}

// Round 5
// 252.560 us; speedup vs baseline: 1.2446x; 1.0605x over previous
//
#include <hip/hip_runtime.h>
#include <hip/hip_bf16.h>

// ============================================================================
// GAT 2-layer forward, round 19.
// r18 post-mortem: seg1f at 2.49TB/s == the measured random-line fill ceiling,
// FETCH == 8-XCD compulsory floor -> seg kernels are AT their roofline
// (~95us combined). Remaining ~173us is the serial CSR chain + gemm1 + gaps,
// none individually top-5 visible. gemm1 is independent of the CSR chain.
// Changes (zero numeric change): (1) k_init removed -> gcur via 784B
// hipMemsetAsync (count semantics), wExt built by one extra block; (2) k_pg
// fuses part(391 blocks) || gemm1-half-A(391) || wExt(1); (3) k_bg fuses
// bucket(196) || gemm1-half-B(391). 5 dispatches, gemm1 fully hidden.
// Facts: fp32 in/out, int32 edge_index, N=100000 E=1600000, bf16 h.
// ============================================================================

typedef __hip_bfloat16 bf16;
typedef unsigned short ushort;
typedef unsigned char uchar;
typedef __attribute__((ext_vector_type(8))) short short8;
typedef __attribute__((ext_vector_type(4))) float f32x4;

#define NN 100000
#define EE 1600000
#define BKB 9
#define BKN (1 << BKB)
#define NBK ((NN + BKN - 1) >> BKB)   // 196
#define CAP 10240                     // arena slots per bucket (max ~8.5K)
#define TILE 4096
#define EPT 16
#define NT ((EE + TILE - 1) / TILE)   // 391 part blocks
#define GH 391                        // gemm1 blocks per fused kernel (half)
#define GT 782                        // gemm1 total block pattern (unchanged)
#define BN 16                         // nodes per seg block (16 | 512 bucket)
#define CHE 512                       // max edges/block: mean 256, +16 sigma

__device__ __forceinline__ float relu_np(float v) { return (v < 0.f) ? 0.f : v; }
__device__ __forceinline__ float lrelu(float v) { return v > 0.f ? v : 0.2f * v; }
__device__ __forceinline__ ushort f2bf(float f) {
    __hip_bfloat16 h = __float2bfloat16(f);
    return *reinterpret_cast<ushort*>(&h);
}
__device__ __forceinline__ float bf2f(ushort u) {
    unsigned int x = ((unsigned int)u) << 16;
    return __uint_as_float(x);
}

// ---- gemm1 body: tile pattern identical to the old 782-block k_gemm1 -------
__device__ __forceinline__ void gemm1_body(
    int gb, ushort* wB, ushort* wE,
    const float* __restrict__ x, const float* __restrict__ W1,
    const float* __restrict__ aS, const float* __restrict__ aD,
    ushort* __restrict__ h1, float* __restrict__ as1, float* __restrict__ ad1)
{
    const int tid = threadIdx.x;
    for (int i = tid; i < 128 * 64; i += 256) {
        int k = i >> 6, n = i & 63;
        wB[n * 128 + k] = f2bf(W1[i]);
    }
    for (int i = tid; i < 128 * 16; i += 256) {
        int k = i >> 4, j = i & 15;
        float v = 0.f;
        if (j < 8) {
            int h = j & 3;
            const float* av = (j < 4) ? aS : aD;
            for (int c = 0; c < 16; ++c)
                v = fmaf(W1[k * 64 + h * 16 + c], av[h * 16 + c], v);
        }
        wE[j * 128 + k] = f2bf(v);
    }
    __syncthreads();
    const int w = tid >> 6, lane = tid & 63;
    const int m = lane & 15, quad = lane >> 4;
    const int ntiles = NN >> 4;
    for (int tile = gb * 4 + w; tile < ntiles; tile += GT * 4) {
        const int row0 = tile << 4;
        f32x4 acc[4] = {f32x4{0,0,0,0}, f32x4{0,0,0,0},
                        f32x4{0,0,0,0}, f32x4{0,0,0,0}};
        f32x4 acc5 = {0, 0, 0, 0};
        const float* xp = x + (size_t)(row0 + m) * 128 + quad * 8;
        #pragma unroll
        for (int ks = 0; ks < 128; ks += 32) {
            f32x4 x0 = *(const f32x4*)(xp + ks);
            f32x4 x1 = *(const f32x4*)(xp + ks + 4);
            short8 a;
            #pragma unroll
            for (int j = 0; j < 4; ++j) a[j] = (short)f2bf(x0[j]);
            #pragma unroll
            for (int j = 0; j < 4; ++j) a[4 + j] = (short)f2bf(x1[j]);
            #pragma unroll
            for (int t = 0; t < 4; ++t) {
                short8 b = *(const short8*)&wB[(t * 16 + m) * 128 + ks + quad * 8];
                acc[t] = __builtin_amdgcn_mfma_f32_16x16x32_bf16(a, b, acc[t], 0, 0, 0);
            }
            short8 b5 = *(const short8*)&wE[m * 128 + ks + quad * 8];
            acc5 = __builtin_amdgcn_mfma_f32_16x16x32_bf16(a, b5, acc5, 0, 0, 0);
        }
        #pragma unroll
        for (int t = 0; t < 4; ++t)
            #pragma unroll
            for (int r = 0; r < 4; ++r)
                h1[(size_t)(row0 + quad * 4 + r) * 64 + t * 16 + m] = f2bf(acc[t][r]);
        #pragma unroll
        for (int r = 0; r < 4; ++r) {
            int row = row0 + quad * 4 + r;
            if (m < 4) as1[row * 4 + m] = acc5[r];
            else if (m < 8) ad1[row * 4 + (m - 4)] = acc5[r];
        }
    }
}

// ---- fused: partition (blocks 0..NT-1) || gemm1 half A || wExt build -------
__global__ __launch_bounds__(256) void k_pg(
    const int* __restrict__ src, const int* __restrict__ dst,
    int* __restrict__ gcur, int* __restrict__ pairs,
    const float* __restrict__ x, const float* __restrict__ W1,
    const float* __restrict__ aS, const float* __restrict__ aD,
    ushort* __restrict__ h1, float* __restrict__ as1, float* __restrict__ ad1,
    const float* __restrict__ W2, const float* __restrict__ aS2,
    const float* __restrict__ aD2, ushort* __restrict__ wExt)
{
    __shared__ ushort wB[64 * 128];
    __shared__ ushort wE[16 * 128];
    __shared__ int lh[NBK];
    __shared__ int lbase[NBK];
    const int bid = blockIdx.x;
    const int tid = threadIdx.x;

    if (bid < NT) {
        // ---- partition into per-bucket arenas (gcur = relative counts) ----
        for (int i = tid; i < NBK; i += 256) lh[i] = 0;
        __syncthreads();
        const int e0 = bid * TILE;
        int pk[EPT], bk[EPT], rv[EPT];
        #pragma unroll
        for (int j = 0; j < EPT; ++j) {
            int e = e0 + j * 256 + tid;
            if (e < EE) {
                int d = dst[e];
                bk[j] = d >> BKB;
                pk[j] = src[e] | ((d & (BKN - 1)) << 17);
                rv[j] = atomicAdd(&lh[bk[j]], 1);
            }
        }
        __syncthreads();
        for (int i = tid; i < NBK; i += 256)
            lbase[i] = lh[i] ? atomicAdd(&gcur[i], lh[i]) : 0;
        __syncthreads();
        #pragma unroll
        for (int j = 0; j < EPT; ++j) {
            int e = e0 + j * 256 + tid;
            if (e < EE)
                pairs[(size_t)bk[j] * CAP + lbase[bk[j]] + rv[j]] = pk[j];
        }
    } else if (bid < NT + GH) {
        gemm1_body(bid - NT, wB, wE, x, W1, aS, aD, h1, as1, ad1);
    } else {
        // ---- wExt^T bf16 [80][64]: n<64: W2 col n; 64: W2@aS2; 65: W2@aD2 --
        for (int i = tid; i < 80 * 64; i += 256) {
            int n = i >> 6, k = i & 63;
            float v = 0.f;
            if (n < 64) {
                v = W2[k * 64 + n];
            } else if (n == 64) {
                for (int c = 0; c < 64; ++c) v = fmaf(W2[k * 64 + c], aS2[c], v);
            } else if (n == 65) {
                for (int c = 0; c < 64; ++c) v = fmaf(W2[k * 64 + c], aD2[c], v);
            }
            wExt[i] = f2bf(v);
        }
    }
}

// ---- fused: per-bucket CSR finalize (blocks 0..NBK-1) || gemm1 half B ------
__global__ __launch_bounds__(256) void k_bg(
    const int* __restrict__ gcur, const int* __restrict__ pairs,
    int* __restrict__ row_ptr, uchar* __restrict__ rcnt,
    int* __restrict__ col,
    const float* __restrict__ x, const float* __restrict__ W1,
    const float* __restrict__ aS, const float* __restrict__ aD,
    ushort* __restrict__ h1, float* __restrict__ as1, float* __restrict__ ad1)
{
    __shared__ ushort wB[64 * 128];
    __shared__ ushort wE[16 * 128];
    __shared__ int hist[BKN];
    __shared__ int sP[256];
    const int bid = blockIdx.x;
    const int tid = threadIdx.x;

    if (bid >= NBK) {
        gemm1_body(bid - NBK + GH, wB, wE, x, W1, aS, aD, h1, as1, ad1);
        return;
    }

    const int b = bid;
    const int n0 = b << BKB;
    const int base = b * CAP, endE = base + gcur[b];
    for (int i = tid; i < BKN; i += 256) hist[i] = 0;
    __syncthreads();
    for (int i = base + tid; i < endE; i += 256)
        atomicAdd(&hist[pairs[i] >> 17], 1);
    __syncthreads();
    int a0 = hist[2 * tid], a1 = hist[2 * tid + 1];
    int tot = a0 + a1;
    sP[tid] = tot;
    __syncthreads();
    for (int off = 1; off < 256; off <<= 1) {
        int t = (tid >= off) ? sP[tid - off] : 0;
        __syncthreads();
        sP[tid] += t;
        __syncthreads();
    }
    const int excl = sP[tid] - tot;
    const int c0 = base + excl;
    hist[2 * tid] = c0;
    hist[2 * tid + 1] = c0 + a0;
    if (n0 + 2 * tid < NN) {
        row_ptr[n0 + 2 * tid] = c0;
        rcnt[n0 + 2 * tid] = (uchar)a0;
    }
    if (n0 + 2 * tid + 1 < NN) {
        row_ptr[n0 + 2 * tid + 1] = c0 + a0;
        rcnt[n0 + 2 * tid + 1] = (uchar)a1;
    }
    __syncthreads();
    for (int i = base + tid; i < endE; i += 256) {
        int pr = pairs[i];
        int p = atomicAdd(&hist[pr >> 17], 1);
        col[p] = pr & 0x1FFFF;
    }
}

// ---------------- layer-1 seg aggregation + fused layer-2 GEMM ---------------
// 16 nodes/block = 4 waves x 4 slot-groups; one node per 16-lane group.
// Lane owns feature cols c4*4..+3 across all its node's edges: no acc/den
// cross-lane reduction. 4-edge unroll -> 4 loads in flight per lane.
// Epilogue: z=relu(acc/den+b1) -> LDS bf16 [16][72]; 10 MFMAs, B from global
// wExt (L2-hot).
__global__ __launch_bounds__(256, 8) void k_seg1f(
    const int* __restrict__ rp, const uchar* __restrict__ rcnt,
    const int* __restrict__ col,
    const float* __restrict__ as1, const float* __restrict__ ad1,
    const ushort* __restrict__ h1, const float* __restrict__ b1,
    const ushort* __restrict__ wExt,
    ushort* __restrict__ h2, float* __restrict__ as2, float* __restrict__ ad2,
    int N)
{
    __shared__ __align__(16) ushort zS[BN * 72];   // z bf16, rows padded 64->72
    __shared__ float pS[CHE * 4];
    __shared__ int colS[CHE];
    __shared__ uchar ndS[CHE];
    __shared__ int sRp[BN + 1];
    __shared__ float bS[64];
    __shared__ float adS[BN * 4];

    const int tid = threadIdx.x;
    const int n0 = blockIdx.x * BN;

    if (tid < 64) bS[tid] = b1[tid];
    if (tid < BN * 4) adS[tid] = ad1[(size_t)n0 * 4 + tid];
    if (tid < BN) sRp[tid] = rp[n0 + tid];
    if (tid == BN) sRp[BN] = rp[n0 + BN - 1] + (int)rcnt[n0 + BN - 1];
    __syncthreads();

    const int eb0 = sRp[0];
    const int cnt = min(sRp[BN] - eb0, CHE);       // mean 256, never near 512

    for (int t = tid; t < cnt; t += 256) {
        int ge = eb0 + t;
        colS[t] = col[ge];
        int nd = 0;
        #pragma unroll
        for (int k = 1; k < BN; ++k) nd += (ge >= sRp[k]);
        ndS[t] = (uchar)nd;
    }
    __syncthreads();
    for (int t = tid; t < cnt * 4; t += 256) {
        int e = t >> 2, hh = t & 3;
        float v = as1[(size_t)colS[e] * 4 + hh] + adS[ndS[e] * 4 + hh];
        pS[t] = __expf(lrelu(v));
    }
    __syncthreads();

    const int w = tid >> 6, lane = tid & 63;
    const int g = lane >> 4, c4 = lane & 15, head = c4 >> 2;
    const int nb = w * 4 + g;
    const int s_n = sRp[nb] - eb0, e_n = sRp[nb + 1] - eb0;

    f32x4 acc = {0, 0, 0, 0};
    float den = 0.f;
    int i = s_n;
    for (; i + 3 < e_n; i += 4) {
        int cA = colS[i], cB = colS[i + 1], cC = colS[i + 2], cD = colS[i + 3];
        ushort4 hA = *(const ushort4*)&h1[(size_t)cA * 64 + c4 * 4];
        ushort4 hB = *(const ushort4*)&h1[(size_t)cB * 64 + c4 * 4];
        ushort4 hC = *(const ushort4*)&h1[(size_t)cC * 64 + c4 * 4];
        ushort4 hD = *(const ushort4*)&h1[(size_t)cD * 64 + c4 * 4];
        float pA = pS[(i + 0) * 4 + head], pB = pS[(i + 1) * 4 + head];
        float pC = pS[(i + 2) * 4 + head], pD = pS[(i + 3) * 4 + head];
        den += (pA + pB) + (pC + pD);
        acc[0] = fmaf(pA, bf2f(hA.x), acc[0]);
        acc[1] = fmaf(pA, bf2f(hA.y), acc[1]);
        acc[2] = fmaf(pA, bf2f(hA.z), acc[2]);
        acc[3] = fmaf(pA, bf2f(hA.w), acc[3]);
        acc[0] = fmaf(pB, bf2f(hB.x), acc[0]);
        acc[1] = fmaf(pB, bf2f(hB.y), acc[1]);
        acc[2] = fmaf(pB, bf2f(hB.z), acc[2]);
        acc[3] = fmaf(pB, bf2f(hB.w), acc[3]);
        acc[0] = fmaf(pC, bf2f(hC.x), acc[0]);
        acc[1] = fmaf(pC, bf2f(hC.y), acc[1]);
        acc[2] = fmaf(pC, bf2f(hC.z), acc[2]);
        acc[3] = fmaf(pC, bf2f(hC.w), acc[3]);
        acc[0] = fmaf(pD, bf2f(hD.x), acc[0]);
        acc[1] = fmaf(pD, bf2f(hD.y), acc[1]);
        acc[2] = fmaf(pD, bf2f(hD.z), acc[2]);
        acc[3] = fmaf(pD, bf2f(hD.w), acc[3]);
    }
    for (; i < e_n; ++i) {
        int cA = colS[i];
        ushort4 hA = *(const ushort4*)&h1[(size_t)cA * 64 + c4 * 4];
        float pA = pS[i * 4 + head];
        den += pA;
        acc[0] = fmaf(pA, bf2f(hA.x), acc[0]);
        acc[1] = fmaf(pA, bf2f(hA.y), acc[1]);
        acc[2] = fmaf(pA, bf2f(hA.z), acc[2]);
        acc[3] = fmaf(pA, bf2f(hA.w), acc[3]);
    }
    {
        float inv = 1.f / (den + 1e-16f);
        ushort4 zv;
        zv.x = f2bf(relu_np(acc[0] * inv + bS[c4 * 4 + 0]));
        zv.y = f2bf(relu_np(acc[1] * inv + bS[c4 * 4 + 1]));
        zv.z = f2bf(relu_np(acc[2] * inv + bS[c4 * 4 + 2]));
        zv.w = f2bf(relu_np(acc[3] * inv + bS[c4 * 4 + 3]));
        *(ushort4*)&zS[nb * 72 + c4 * 4] = zv;
    }
    __syncthreads();

    // ---- fused gemm2 epilogue: 5 n-tiles over 4 waves (wave0 takes ext) ----
    // B fragments straight from global wExt [80][64] (L2-hot, 16B aligned).
    const int m = c4, quad = g;
    for (int t = w; t < 5; t += 4) {
        f32x4 acct = {0, 0, 0, 0};
        #pragma unroll
        for (int ks = 0; ks < 64; ks += 32) {
            short8 a = *(const short8*)&zS[m * 72 + ks + quad * 8];
            short8 b = *(const short8*)&wExt[(t * 16 + m) * 64 + ks + quad * 8];
            acct = __builtin_amdgcn_mfma_f32_16x16x32_bf16(a, b, acct, 0, 0, 0);
        }
        if (t < 4) {
            #pragma unroll
            for (int r = 0; r < 4; ++r)
                h2[(size_t)(n0 + quad * 4 + r) * 64 + t * 16 + m] = f2bf(acct[r]);
        } else {
            #pragma unroll
            for (int r = 0; r < 4; ++r) {
                int row = n0 + quad * 4 + r;
                if (m == 0) as2[row] = acct[r];
                else if (m == 1) ad2[row] = acct[r];
            }
        }
    }
}

// ---------------- layer-2 seg aggregation + fused classifier head -----------
// Same one-node-per-16-lane-group structure; only the classifier dot product
// needs a cross-lane (4-shuffle) reduce.
__global__ __launch_bounds__(256, 8) void k_seg2f(
    const int* __restrict__ rp, const uchar* __restrict__ rcnt,
    const int* __restrict__ col,
    const float* __restrict__ as2, const float* __restrict__ ad2,
    const ushort* __restrict__ h2, const float* __restrict__ b2,
    const float* __restrict__ Wc, const float* __restrict__ bc,
    float* __restrict__ out, int N)
{
    __shared__ float pS[CHE];
    __shared__ int colS[CHE];
    __shared__ uchar ndS[CHE];
    __shared__ int sRp[BN + 1];
    __shared__ float adS[BN];
    __shared__ float b2S[64];
    __shared__ float wcS[64];

    const int tid = threadIdx.x;
    const int n0 = blockIdx.x * BN;
    if (tid < 64) { b2S[tid] = b2[tid]; wcS[tid] = Wc[tid]; }
    if (tid < BN) { sRp[tid] = rp[n0 + tid]; adS[tid] = ad2[n0 + tid]; }
    if (tid == BN) sRp[BN] = rp[n0 + BN - 1] + (int)rcnt[n0 + BN - 1];
    __syncthreads();

    const int eb0 = sRp[0];
    const int cnt = min(sRp[BN] - eb0, CHE);
    for (int t = tid; t < cnt; t += 256) {
        int ge = eb0 + t;
        colS[t] = col[ge];
        int nd = 0;
        #pragma unroll
        for (int k = 1; k < BN; ++k) nd += (ge >= sRp[k]);
        ndS[t] = (uchar)nd;
    }
    __syncthreads();
    for (int t = tid; t < cnt; t += 256)
        pS[t] = __expf(lrelu(as2[colS[t]] + adS[ndS[t]]));
    __syncthreads();

    const int w = tid >> 6, lane = tid & 63;
    const int g = lane >> 4, c4 = lane & 15;
    const int nb = w * 4 + g;
    const int myn = n0 + nb;
    const int s_n = sRp[nb] - eb0, e_n = sRp[nb + 1] - eb0;

    f32x4 acc = {0, 0, 0, 0};
    float den = 0.f;
    int i = s_n;
    for (; i + 3 < e_n; i += 4) {
        int cA = colS[i], cB = colS[i + 1], cC = colS[i + 2], cD = colS[i + 3];
        ushort4 hA = *(const ushort4*)&h2[(size_t)cA * 64 + c4 * 4];
        ushort4 hB = *(const ushort4*)&h2[(size_t)cB * 64 + c4 * 4];
        ushort4 hC = *(const ushort4*)&h2[(size_t)cC * 64 + c4 * 4];
        ushort4 hD = *(const ushort4*)&h2[(size_t)cD * 64 + c4 * 4];
        float pA = pS[i + 0], pB = pS[i + 1], pC = pS[i + 2], pD = pS[i + 3];
        den += (pA + pB) + (pC + pD);
        acc[0] = fmaf(pA, bf2f(hA.x), acc[0]);
        acc[1] = fmaf(pA, bf2f(hA.y), acc[1]);
        acc[2] = fmaf(pA, bf2f(hA.z), acc[2]);
        acc[3] = fmaf(pA, bf2f(hA.w), acc[3]);
        acc[0] = fmaf(pB, bf2f(hB.x), acc[0]);
        acc[1] = fmaf(pB, bf2f(hB.y), acc[1]);
        acc[2] = fmaf(pB, bf2f(hB.z), acc[2]);
        acc[3] = fmaf(pB, bf2f(hB.w), acc[3]);
        acc[0] = fmaf(pC, bf2f(hC.x), acc[0]);
        acc[1] = fmaf(pC, bf2f(hC.y), acc[1]);
        acc[2] = fmaf(pC, bf2f(hC.z), acc[2]);
        acc[3] = fmaf(pC, bf2f(hC.w), acc[3]);
        acc[0] = fmaf(pD, bf2f(hD.x), acc[0]);
        acc[1] = fmaf(pD, bf2f(hD.y), acc[1]);
        acc[2] = fmaf(pD, bf2f(hD.z), acc[2]);
        acc[3] = fmaf(pD, bf2f(hD.w), acc[3]);
    }
    for (; i < e_n; ++i) {
        int cA = colS[i];
        ushort4 hA = *(const ushort4*)&h2[(size_t)cA * 64 + c4 * 4];
        float pA = pS[i];
        den += pA;
        acc[0] = fmaf(pA, bf2f(hA.x), acc[0]);
        acc[1] = fmaf(pA, bf2f(hA.y), acc[1]);
        acc[2] = fmaf(pA, bf2f(hA.z), acc[2]);
        acc[3] = fmaf(pA, bf2f(hA.w), acc[3]);
    }

    float inv = 1.f / (den + 1e-16f);
    float t2 = 0.f;
    #pragma unroll
    for (int j = 0; j < 4; ++j)
        t2 += relu_np(acc[j] * inv + b2S[c4 * 4 + j]) * wcS[c4 * 4 + j];
    t2 += __shfl_xor(t2, 1);
    t2 += __shfl_xor(t2, 2);
    t2 += __shfl_xor(t2, 4);
    t2 += __shfl_xor(t2, 8);
    if (c4 == 0) out[myn] = t2 + bc[0];
}

extern "C" void kernel_launch(void* const* d_in, const int* in_sizes, int n_in,
                              void* d_out, int out_size, void* d_ws, size_t ws_size,
                              hipStream_t stream)
{
    const float* x   = (const float*)d_in[0];
    const int*   ei  = (const int*)d_in[1];
    const float* W1  = (const float*)d_in[2];
    const float* aS1 = (const float*)d_in[3];
    const float* aD1 = (const float*)d_in[4];
    const float* b1  = (const float*)d_in[5];
    const float* W2  = (const float*)d_in[6];
    const float* aS2 = (const float*)d_in[7];
    const float* aD2 = (const float*)d_in[8];
    const float* b2  = (const float*)d_in[9];
    const float* Wc  = (const float*)d_in[10];
    const float* bc  = (const float*)d_in[11];
    float* out = (float*)d_out;

    const int N = NN;
    const int E = EE;
    const int* src = ei;
    const int* dst = ei + E;

    // ---- workspace layout (~36 MB) ----
    ushort* h1   = (ushort*)d_ws;                     // [N*64] bf16  12.8MB
    ushort* h2   = h1 + (size_t)N * 64;               // [N*64] bf16  12.8MB
    float*  as1  = (float*)(h2 + (size_t)N * 64);     // [4N]
    float*  ad1  = as1 + (size_t)N * 4;               // [4N]
    float*  as2  = ad1 + (size_t)N * 4;               // [N]
    float*  ad2  = as2 + (size_t)N;                   // [N]
    ushort* wExt = (ushort*)(ad2 + (size_t)N);        // [80*64] bf16 10KB
    int* row_ptr = (int*)(wExt + 80 * 64);            // [N]
    uchar* rcnt  = (uchar*)(row_ptr + N);             // [N] bytes
    int* gcur    = (int*)(rcnt + ((N + 3) & ~3));     // [NBK] relative counts
    int* col     = gcur + NBK;                        // [NBK*CAP] 8MB arena
    int* pairs   = (int*)h2;                          // aliases h2 (dead by seg1f)

    // ---- stage 0: zero bucket counters (784 B) ----
    hipMemsetAsync(gcur, 0, NBK * sizeof(int), stream);

    // ---- stage 1: partition || gemm1 half A || wExt build ----
    k_pg<<<NT + GH + 1, 256, 0, stream>>>(src, dst, gcur, pairs,
                                          x, W1, aS1, aD1, h1, as1, ad1,
                                          W2, aS2, aD2, wExt);

    // ---- stage 2: bucket CSR finalize || gemm1 half B ----
    k_bg<<<NBK + GH, 256, 0, stream>>>(gcur, pairs, row_ptr, rcnt, col,
                                       x, W1, aS1, aD1, h1, as1, ad1);

    // ---- stage 3: layer 1 aggregation + fused layer 2 GEMM ----
    k_seg1f<<<N / BN, 256, 0, stream>>>(row_ptr, rcnt, col, as1, ad1, h1, b1,
                                        wExt, h2, as2, ad2, N);

    // ---- stage 4: layer 2 aggregation + fused classifier ----
    k_seg2f<<<N / BN, 256, 0, stream>>>(row_ptr, rcnt, col, as2, ad2, h2,
                                        b2, Wc, bc, out, N);
}